// Round 1
// baseline (858.672 us; speedup 1.0000x reference)
//
#include <hip/hip_runtime.h>
#include <math.h>

#define F_IN 512
#define H1 16
#define C_OUT 7

// ---------------- degree / norm ----------------
__global__ void k_deg_init(float* __restrict__ deg, int n) {
    int i = blockIdx.x * 256 + threadIdx.x;
    if (i < n) deg[i] = 1.0f;   // self-loop
}

__global__ void k_deg_count(const int* __restrict__ dst, float* __restrict__ deg, int E) {
    int e = blockIdx.x * 256 + threadIdx.x;
    if (e < E) atomicAdd(&deg[dst[e]], 1.0f);
}

__global__ void k_dinv(const float* __restrict__ deg, float* __restrict__ dinv, int n) {
    int i = blockIdx.x * 256 + threadIdx.x;
    if (i < n) dinv[i] = rsqrtf(deg[i]);
}

// ---------------- GEMM1: h1 = x @ W1 ; out1 = h1*dinv^2 + b1 ----------------
// block = 256 threads = 256 rows. LDS tile transposed xs[k][row], pitch 257.
__global__ __launch_bounds__(256) void k_gemm1(
    const float* __restrict__ x, const float* __restrict__ W1,
    const float* __restrict__ b1, const float* __restrict__ dinv,
    float* __restrict__ h1, float* __restrict__ out1, int n) {
    __shared__ float xs[32 * 257];
    const int tid = threadIdx.x;
    const int rowbase = blockIdx.x * 256;
    const int row = rowbase + tid;

    float acc[H1];
#pragma unroll
    for (int c = 0; c < H1; c++) acc[c] = 0.0f;

    for (int kc = 0; kc < F_IN; kc += 32) {
        __syncthreads();
        // cooperative staged load: 256 rows x 32 k = 2048 float4 slots
#pragma unroll
        for (int j = 0; j < 8; j++) {
            int flat = tid + 256 * j;      // float4 slot id
            int r = flat >> 3;             // local row 0..255
            int kq = flat & 7;             // float4 within the 32-k chunk
            int grow = rowbase + r;
            float4 v = make_float4(0.f, 0.f, 0.f, 0.f);
            if (grow < n) v = *(const float4*)(x + (size_t)grow * F_IN + kc + kq * 4);
            xs[(kq * 4 + 0) * 257 + r] = v.x;
            xs[(kq * 4 + 1) * 257 + r] = v.y;
            xs[(kq * 4 + 2) * 257 + r] = v.z;
            xs[(kq * 4 + 3) * 257 + r] = v.w;
        }
        __syncthreads();
#pragma unroll 4
        for (int k = 0; k < 32; k++) {
            float xv = xs[k * 257 + tid];
            const float* w = W1 + (kc + k) * H1;   // uniform address -> s_load
#pragma unroll
            for (int c = 0; c < H1; c++) acc[c] = fmaf(xv, w[c], acc[c]);
        }
    }

    if (row < n) {
        float d = dinv[row];
        float sn = d * d;
#pragma unroll
        for (int c = 0; c < H1; c++) {
            h1[(size_t)row * H1 + c] = acc[c];
            out1[(size_t)row * H1 + c] = fmaf(acc[c], sn, b1[c]);
        }
    }
}

// ---------------- edge scatter layer 1: out1[dst] += h1[src]*norm ----------------
__global__ void k_scatter1(const int* __restrict__ src, const int* __restrict__ dst,
                           const float* __restrict__ dinv,
                           const float* __restrict__ h1, float* __restrict__ out1, int E) {
    int t = blockIdx.x * 256 + threadIdx.x;
    int e = t >> 4;
    int c = t & 15;
    if (e >= E) return;
    int s = src[e];
    int d = dst[e];
    float nrm = dinv[s] * dinv[d];
    atomicAdd(&out1[(size_t)d * H1 + c], h1[(size_t)s * H1 + c] * nrm);
}

// ---------------- GEMM2: h2 = relu(out1) @ W2 ; out2 = h2*dinv^2 + b2 (stride 8) ----------------
__global__ __launch_bounds__(256) void k_gemm2(
    const float* __restrict__ out1, const float* __restrict__ W2,
    const float* __restrict__ b2, const float* __restrict__ dinv,
    float* __restrict__ h2, float* __restrict__ out2, int n) {
    __shared__ float xs[16 * 257];
    const int tid = threadIdx.x;
    const int rowbase = blockIdx.x * 256;
    const int row = rowbase + tid;

    // stage 256 rows x 16 cols = 1024 float4 slots, relu applied on load
#pragma unroll
    for (int j = 0; j < 4; j++) {
        int flat = tid + 256 * j;
        int r = flat >> 2;       // local row
        int kq = flat & 3;       // float4 within 16
        int grow = rowbase + r;
        float4 v = make_float4(0.f, 0.f, 0.f, 0.f);
        if (grow < n) v = *(const float4*)(out1 + (size_t)grow * H1 + kq * 4);
        xs[(kq * 4 + 0) * 257 + r] = fmaxf(v.x, 0.f);
        xs[(kq * 4 + 1) * 257 + r] = fmaxf(v.y, 0.f);
        xs[(kq * 4 + 2) * 257 + r] = fmaxf(v.z, 0.f);
        xs[(kq * 4 + 3) * 257 + r] = fmaxf(v.w, 0.f);
    }
    __syncthreads();

    float acc[C_OUT];
#pragma unroll
    for (int c = 0; c < C_OUT; c++) acc[c] = 0.0f;
#pragma unroll
    for (int k = 0; k < H1; k++) {
        float xv = xs[k * 257 + tid];
        const float* w = W2 + k * C_OUT;   // uniform -> s_load
#pragma unroll
        for (int c = 0; c < C_OUT; c++) acc[c] = fmaf(xv, w[c], acc[c]);
    }

    if (row < n) {
        float d = dinv[row];
        float sn = d * d;
#pragma unroll
        for (int c = 0; c < C_OUT; c++) {
            h2[(size_t)row * 8 + c] = acc[c];
            out2[(size_t)row * 8 + c] = fmaf(acc[c], sn, b2[c]);
        }
        h2[(size_t)row * 8 + 7] = 0.0f;
        out2[(size_t)row * 8 + 7] = 0.0f;
    }
}

// ---------------- edge scatter layer 2 ----------------
__global__ void k_scatter2(const int* __restrict__ src, const int* __restrict__ dst,
                           const float* __restrict__ dinv,
                           const float* __restrict__ h2, float* __restrict__ out2, int E) {
    int t = blockIdx.x * 256 + threadIdx.x;
    int e = t >> 3;
    int c = t & 7;
    if (e >= E) return;
    if (c >= C_OUT) return;
    int s = src[e];
    int d = dst[e];
    float nrm = dinv[s] * dinv[d];
    atomicAdd(&out2[(size_t)d * 8 + c], h2[(size_t)s * 8 + c] * nrm);
}

// ---------------- log_softmax over 7 cols ----------------
__global__ void k_lsm(const float* __restrict__ out2, float* __restrict__ out, int n) {
    int i = blockIdx.x * 256 + threadIdx.x;
    if (i >= n) return;
    float v[C_OUT];
    float m = -1e30f;
#pragma unroll
    for (int c = 0; c < C_OUT; c++) {
        v[c] = out2[(size_t)i * 8 + c];
        m = fmaxf(m, v[c]);
    }
    float s = 0.0f;
#pragma unroll
    for (int c = 0; c < C_OUT; c++) s += expf(v[c] - m);
    float l = logf(s) + m;
#pragma unroll
    for (int c = 0; c < C_OUT; c++) out[(size_t)i * C_OUT + c] = v[c] - l;
}

extern "C" void kernel_launch(void* const* d_in, const int* in_sizes, int n_in,
                              void* d_out, int out_size, void* d_ws, size_t ws_size,
                              hipStream_t stream) {
    const float* x  = (const float*)d_in[0];
    const int* ei   = (const int*)d_in[1];
    const float* W1 = (const float*)d_in[2];
    const float* b1 = (const float*)d_in[3];
    const float* W2 = (const float*)d_in[4];
    const float* b2 = (const float*)d_in[5];
    float* out = (float*)d_out;

    const int n = in_sizes[0] / F_IN;     // 100000
    const int E = in_sizes[1] / 2;        // 3200000
    const int* src = ei;
    const int* dst = ei + E;

    // workspace layout (floats)
    float* w = (float*)d_ws;
    float* deg  = w;                 // n
    float* dinv = w + (size_t)n;     // n
    float* h1   = w + (size_t)2 * n;       // n*16
    float* out1 = w + (size_t)18 * n;      // n*16
    float* h2   = w + (size_t)34 * n;      // n*8
    float* out2 = w + (size_t)42 * n;      // n*8  (total 50n floats = 20 MB)

    const int nbN = (n + 255) / 256;
    const int nbE = (E + 255) / 256;

    k_deg_init<<<nbN, 256, 0, stream>>>(deg, n);
    k_deg_count<<<nbE, 256, 0, stream>>>(dst, deg, E);
    k_dinv<<<nbN, 256, 0, stream>>>(deg, dinv, n);

    k_gemm1<<<nbN, 256, 0, stream>>>(x, W1, b1, dinv, h1, out1, n);
    {
        long long t = (long long)E * 16;
        int nb = (int)((t + 255) / 256);
        k_scatter1<<<nb, 256, 0, stream>>>(src, dst, dinv, h1, out1, E);
    }
    k_gemm2<<<nbN, 256, 0, stream>>>(out1, W2, b2, dinv, h2, out2, n);
    {
        long long t = (long long)E * 8;
        int nb = (int)((t + 255) / 256);
        k_scatter2<<<nb, 256, 0, stream>>>(src, dst, dinv, h2, out2, E);
    }
    k_lsm<<<nbN, 256, 0, stream>>>(out2, out, n);
}

// Round 2
// 818.456 us; speedup vs baseline: 1.0491x; 1.0491x over previous
//
#include <hip/hip_runtime.h>
#include <math.h>

#define F_IN 512
#define H1 16
#define C_OUT 7

// ---------------- zero int array ----------------
__global__ void k_zero(int* __restrict__ p, int n) {
    int i = blockIdx.x * 256 + threadIdx.x;
    if (i < n) p[i] = 0;
}

// ---------------- in-degree histogram ----------------
__global__ void k_hist(const int* __restrict__ dst, int* __restrict__ indeg, int E) {
    int e = blockIdx.x * 256 + threadIdx.x;
    if (e < E) atomicAdd(&indeg[dst[e]], 1);
}

// ---------------- dinv = rsqrt(1 + indeg) ----------------
__global__ void k_dinv(const int* __restrict__ indeg, float* __restrict__ dinv, int n) {
    int i = blockIdx.x * 256 + threadIdx.x;
    if (i < n) dinv[i] = rsqrtf(1.0f + (float)indeg[i]);
}

// ---------------- 2-level exclusive scan ----------------
__global__ void k_scan1(const int* __restrict__ indeg, int* __restrict__ excl,
                        int* __restrict__ blocksum, int n) {
    __shared__ int s[256];
    int i = blockIdx.x * 256 + threadIdx.x;
    int v = (i < n) ? indeg[i] : 0;
    s[threadIdx.x] = v;
    __syncthreads();
#pragma unroll
    for (int off = 1; off < 256; off <<= 1) {
        int t = (threadIdx.x >= off) ? s[threadIdx.x - off] : 0;
        __syncthreads();
        s[threadIdx.x] += t;
        __syncthreads();
    }
    if (i < n) excl[i] = s[threadIdx.x] - v;   // exclusive within block
    if (threadIdx.x == 255) blocksum[blockIdx.x] = s[255];
}

__global__ void k_scan2(int* __restrict__ blocksum, int nb) {
    __shared__ int s[512];
    int v = (threadIdx.x < nb) ? blocksum[threadIdx.x] : 0;
    s[threadIdx.x] = v;
    __syncthreads();
#pragma unroll
    for (int off = 1; off < 512; off <<= 1) {
        int t = (threadIdx.x >= off) ? s[threadIdx.x - off] : 0;
        __syncthreads();
        s[threadIdx.x] += t;
        __syncthreads();
    }
    if (threadIdx.x < nb) blocksum[threadIdx.x] = s[threadIdx.x] - v;  // exclusive
}

__global__ void k_scan3(int* __restrict__ rowptr, int* __restrict__ cursor,
                        const int* __restrict__ blocksum, int n) {
    int i = blockIdx.x * 256 + threadIdx.x;
    if (i < n) {
        int v = rowptr[i] + blocksum[blockIdx.x];
        rowptr[i] = v;
        cursor[i] = v;
    }
}

// ---------------- CSR fill: csr_src[pos] = src ----------------
__global__ void k_fill(const int* __restrict__ src, const int* __restrict__ dst,
                       int* __restrict__ cursor, int* __restrict__ csr_src, int E) {
    int e = blockIdx.x * 256 + threadIdx.x;
    if (e >= E) return;
    int d = dst[e];
    int pos = atomicAdd(&cursor[d], 1);
    csr_src[pos] = src[e];
}

// ---------------- GEMM1: g1 = dinv * (x @ W1) ----------------
__global__ __launch_bounds__(256) void k_gemm1(
    const float* __restrict__ x, const float* __restrict__ W1,
    const float* __restrict__ dinv, float* __restrict__ g1, int n) {
    __shared__ float xs[32 * 257];
    const int tid = threadIdx.x;
    const int rowbase = blockIdx.x * 256;
    const int row = rowbase + tid;

    float acc[H1];
#pragma unroll
    for (int c = 0; c < H1; c++) acc[c] = 0.0f;

    for (int kc = 0; kc < F_IN; kc += 32) {
        __syncthreads();
#pragma unroll
        for (int j = 0; j < 8; j++) {
            int flat = tid + 256 * j;
            int r = flat >> 3;
            int kq = flat & 7;
            int grow = rowbase + r;
            float4 v = make_float4(0.f, 0.f, 0.f, 0.f);
            if (grow < n) v = *(const float4*)(x + (size_t)grow * F_IN + kc + kq * 4);
            xs[(kq * 4 + 0) * 257 + r] = v.x;
            xs[(kq * 4 + 1) * 257 + r] = v.y;
            xs[(kq * 4 + 2) * 257 + r] = v.z;
            xs[(kq * 4 + 3) * 257 + r] = v.w;
        }
        __syncthreads();
#pragma unroll 4
        for (int k = 0; k < 32; k++) {
            float xv = xs[k * 257 + tid];
            const float* w = W1 + (kc + k) * H1;
#pragma unroll
            for (int c = 0; c < H1; c++) acc[c] = fmaf(xv, w[c], acc[c]);
        }
    }

    if (row < n) {
        float d = dinv[row];
#pragma unroll
        for (int c = 0; c < H1; c++) g1[(size_t)row * H1 + c] = acc[c] * d;
    }
}

// ---------------- aggregation layer 1 (pull), fused ReLU ----------------
// 16 lanes per node; lane c handles column c. r1 = relu(dinv[d]*(sum+self) + b1)
__global__ __launch_bounds__(256) void k_agg1(
    const int* __restrict__ rowptr, const int* __restrict__ indeg,
    const int* __restrict__ csr_src, const float* __restrict__ g1,
    const float* __restrict__ dinv, const float* __restrict__ b1,
    float* __restrict__ r1, int n) {
    int grp = threadIdx.x >> 4;
    int c = threadIdx.x & 15;
    int node = blockIdx.x * 16 + grp;
    if (node >= n) return;
    int start = rowptr[node];
    int end = start + indeg[node];
    float s0 = g1[(size_t)node * H1 + c];   // self-loop term
    float s1 = 0.f, s2 = 0.f, s3 = 0.f;
    int i = start;
    for (; i + 3 < end; i += 4) {
        int a0 = csr_src[i];
        int a1 = csr_src[i + 1];
        int a2 = csr_src[i + 2];
        int a3 = csr_src[i + 3];
        s0 += g1[(size_t)a0 * H1 + c];
        s1 += g1[(size_t)a1 * H1 + c];
        s2 += g1[(size_t)a2 * H1 + c];
        s3 += g1[(size_t)a3 * H1 + c];
    }
    for (; i < end; i++) s0 += g1[(size_t)csr_src[i] * H1 + c];
    float sum = (s0 + s1) + (s2 + s3);
    float val = fmaf(dinv[node], sum, b1[c]);
    r1[(size_t)node * H1 + c] = fmaxf(val, 0.0f);
}

// ---------------- GEMM2: g2 = dinv * (r1 @ W2), stride 8, col7 = 0 ----------------
__global__ __launch_bounds__(256) void k_gemm2(
    const float* __restrict__ r1, const float* __restrict__ W2,
    const float* __restrict__ dinv, float* __restrict__ g2, int n) {
    __shared__ float xs[16 * 257];
    const int tid = threadIdx.x;
    const int rowbase = blockIdx.x * 256;
    const int row = rowbase + tid;

#pragma unroll
    for (int j = 0; j < 4; j++) {
        int flat = tid + 256 * j;
        int r = flat >> 2;
        int kq = flat & 3;
        int grow = rowbase + r;
        float4 v = make_float4(0.f, 0.f, 0.f, 0.f);
        if (grow < n) v = *(const float4*)(r1 + (size_t)grow * H1 + kq * 4);
        xs[(kq * 4 + 0) * 257 + r] = v.x;
        xs[(kq * 4 + 1) * 257 + r] = v.y;
        xs[(kq * 4 + 2) * 257 + r] = v.z;
        xs[(kq * 4 + 3) * 257 + r] = v.w;
    }
    __syncthreads();

    float acc[C_OUT];
#pragma unroll
    for (int c = 0; c < C_OUT; c++) acc[c] = 0.0f;
#pragma unroll
    for (int k = 0; k < H1; k++) {
        float xv = xs[k * 257 + tid];
        const float* w = W2 + k * C_OUT;
#pragma unroll
        for (int c = 0; c < C_OUT; c++) acc[c] = fmaf(xv, w[c], acc[c]);
    }

    if (row < n) {
        float d = dinv[row];
#pragma unroll
        for (int c = 0; c < C_OUT; c++) g2[(size_t)row * 8 + c] = acc[c] * d;
        g2[(size_t)row * 8 + 7] = 0.0f;
    }
}

// ---------------- aggregation layer 2 (pull) + fused log_softmax ----------------
// 8 lanes per node; lane c handles column c (c==7 is padding).
__global__ __launch_bounds__(256) void k_agg2(
    const int* __restrict__ rowptr, const int* __restrict__ indeg,
    const int* __restrict__ csr_src, const float* __restrict__ g2,
    const float* __restrict__ dinv, const float* __restrict__ b2,
    float* __restrict__ out, int n) {
    int grp = threadIdx.x >> 3;
    int c = threadIdx.x & 7;
    int node = blockIdx.x * 32 + grp;
    if (node >= n) return;
    int start = rowptr[node];
    int end = start + indeg[node];
    float s0 = g2[(size_t)node * 8 + c];    // self-loop
    float s1 = 0.f, s2 = 0.f, s3 = 0.f;
    int i = start;
    for (; i + 3 < end; i += 4) {
        int a0 = csr_src[i];
        int a1 = csr_src[i + 1];
        int a2 = csr_src[i + 2];
        int a3 = csr_src[i + 3];
        s0 += g2[(size_t)a0 * 8 + c];
        s1 += g2[(size_t)a1 * 8 + c];
        s2 += g2[(size_t)a2 * 8 + c];
        s3 += g2[(size_t)a3 * 8 + c];
    }
    for (; i < end; i++) s0 += g2[(size_t)csr_src[i] * 8 + c];
    float sum = (s0 + s1) + (s2 + s3);
    float bc = (c < C_OUT) ? b2[c] : 0.0f;
    float val = fmaf(dinv[node], sum, bc);

    // log_softmax across lanes 0..6 of this 8-lane group
    float v = (c < C_OUT) ? val : -1e30f;
    float m = v;
#pragma unroll
    for (int o = 1; o < 8; o <<= 1) m = fmaxf(m, __shfl_xor(m, o, 8));
    float ex = (c < C_OUT) ? expf(val - m) : 0.0f;
    float se = ex;
#pragma unroll
    for (int o = 1; o < 8; o <<= 1) se += __shfl_xor(se, o, 8);
    float l = logf(se) + m;
    if (c < C_OUT) out[(size_t)node * C_OUT + c] = val - l;
}

extern "C" void kernel_launch(void* const* d_in, const int* in_sizes, int n_in,
                              void* d_out, int out_size, void* d_ws, size_t ws_size,
                              hipStream_t stream) {
    const float* x  = (const float*)d_in[0];
    const int* ei   = (const int*)d_in[1];
    const float* W1 = (const float*)d_in[2];
    const float* b2 = (const float*)d_in[5];
    const float* b1 = (const float*)d_in[3];
    const float* W2 = (const float*)d_in[4];
    float* out = (float*)d_out;

    const int n = in_sizes[0] / F_IN;     // 100000
    const int E = in_sizes[1] / 2;        // 3200000
    const int* src = ei;
    const int* dst = ei + E;

    // workspace layout (4-byte units)
    char* w = (char*)d_ws;
    int*   indeg   = (int*)w;                              // n
    int*   rowptr  = indeg + n;                            // n
    int*   cursor  = rowptr + n;                           // n
    float* dinv    = (float*)(cursor + n);                 // n
    float* g1      = dinv + n;                             // 16n (reused as g2: 8n)
    float* r1      = g1 + (size_t)16 * n;                  // 16n
    int*   blocksum = (int*)(r1 + (size_t)16 * n);         // 512
    int*   csr_src = blocksum + 512;                       // E
    float* g2      = g1;                                   // alias (g1 dead after agg1... see order)

    const int nbN = (n + 255) / 256;   // 391
    const int nbE = (E + 255) / 256;   // 12500

    k_zero<<<nbN, 256, 0, stream>>>(indeg, n);
    k_hist<<<nbE, 256, 0, stream>>>(dst, indeg, E);
    k_dinv<<<nbN, 256, 0, stream>>>(indeg, dinv, n);
    k_scan1<<<nbN, 256, 0, stream>>>(indeg, rowptr, blocksum, n);
    k_scan2<<<1, 512, 0, stream>>>(blocksum, nbN);
    k_scan3<<<nbN, 256, 0, stream>>>(rowptr, cursor, blocksum, n);
    k_fill<<<nbE, 256, 0, stream>>>(src, dst, cursor, csr_src, E);

    k_gemm1<<<nbN, 256, 0, stream>>>(x, W1, dinv, g1, n);
    k_agg1<<<(n + 15) / 16, 256, 0, stream>>>(rowptr, indeg, csr_src, g1, dinv, b1, r1, n);
    k_gemm2<<<nbN, 256, 0, stream>>>(r1, W2, dinv, g2, n);   // overwrites g1 (dead)
    k_agg2<<<(n + 31) / 32, 256, 0, stream>>>(rowptr, indeg, csr_src, g2, dinv, b2, out, n);
}